// Round 1
// 238.493 us; speedup vs baseline: 1.1012x; 1.1012x over previous
//
#include <hip/hip_runtime.h>
#include <hip/hip_bf16.h>
#include <math.h>

#define NQ 6144
#define MR 6144
#define DIN 16
#define HID 256
#define INV_T 10.0f

typedef __attribute__((ext_vector_type(4))) float f32x4;
typedef __attribute__((ext_vector_type(8))) short bf16x8;

static __device__ __forceinline__ unsigned short f2bf(float f) {
  __hip_bfloat16 h = __float2bfloat16(f);
  return __builtin_bit_cast(unsigned short, h);
}

// ---------------------------------------------------------------------------
// K1: compress both q and ret rows: t = gelu(x@W1^T + b1); h = t@W2^T + b2.
// For q rows additionally g = h @ Wb (written bf16). For ret rows h written bf16.
// 16 rows per block, 256 threads.
// ---------------------------------------------------------------------------
__global__ __launch_bounds__(256) void k_compress(
    const float* __restrict__ q, const float* __restrict__ ret,
    const float* __restrict__ W1, const float* __restrict__ b1,
    const float* __restrict__ W2, const float* __restrict__ b2,
    const float* __restrict__ Wb,
    unsigned short* __restrict__ g_bf, unsigned short* __restrict__ hr_bf)
{
  const int tid = threadIdx.x;
  const bool is_q = blockIdx.x < (NQ / 16);
  const int row0 = (is_q ? blockIdx.x : blockIdx.x - NQ / 16) * 16;
  const float* x = is_q ? q : ret;

  __shared__ float xs[16][DIN];
  __shared__ float ts[16][HID];
  __shared__ float hs[16][HID];

  xs[tid >> 4][tid & 15] = x[(size_t)(row0 + (tid >> 4)) * DIN + (tid & 15)];
  __syncthreads();

  // phase 1: t[r][tid] = gelu(dot(x[r], W1[tid]) + b1[tid])
  {
    float w[DIN];
#pragma unroll
    for (int d = 0; d < DIN; ++d) w[d] = W1[tid * DIN + d];
    const float bb = b1[tid];
#pragma unroll
    for (int rr = 0; rr < 16; ++rr) {
      float acc = bb;
#pragma unroll
      for (int d = 0; d < DIN; ++d) acc += xs[rr][d] * w[d];
      ts[rr][tid] = 0.5f * acc * (1.0f + erff(acc * 0.70710678118654752f));
    }
  }
  __syncthreads();

  // phase 2: h[r][tid] = dot(t[r], W2[tid]) + b2[tid]
  {
    float acc[16];
    const float bb = b2[tid];
#pragma unroll
    for (int rr = 0; rr < 16; ++rr) acc[rr] = bb;
    for (int j = 0; j < HID; j += 4) {
      const f32x4 w = *(const f32x4*)(&W2[(size_t)tid * HID + j]);
#pragma unroll
      for (int rr = 0; rr < 16; ++rr) {
        const f32x4 t4 = *(const f32x4*)(&ts[rr][j]);
        acc[rr] += t4.x * w.x + t4.y * w.y + t4.z * w.z + t4.w * w.w;
      }
    }
#pragma unroll
    for (int rr = 0; rr < 16; ++rr) hs[rr][tid] = acc[rr];
  }
  __syncthreads();

  if (!is_q) {
#pragma unroll
    for (int rr = 0; rr < 16; ++rr)
      hr_bf[(size_t)(row0 + rr) * HID + tid] = f2bf(hs[rr][tid]);
    return;
  }

  // phase 3 (q only): g[r][tid] = sum_j h[r][j] * Wb[j][tid]
  {
    float acc[16];
#pragma unroll
    for (int rr = 0; rr < 16; ++rr) acc[rr] = 0.0f;
    for (int j = 0; j < HID; j += 4) {
      const float w0 = Wb[(size_t)(j + 0) * HID + tid];
      const float w1 = Wb[(size_t)(j + 1) * HID + tid];
      const float w2 = Wb[(size_t)(j + 2) * HID + tid];
      const float w3 = Wb[(size_t)(j + 3) * HID + tid];
#pragma unroll
      for (int rr = 0; rr < 16; ++rr) {
        const f32x4 h4 = *(const f32x4*)(&hs[rr][j]);
        acc[rr] += h4.x * w0 + h4.y * w1 + h4.z * w2 + h4.w * w3;
      }
    }
#pragma unroll
    for (int rr = 0; rr < 16; ++rr)
      g_bf[(size_t)(row0 + rr) * HID + tid] = f2bf(acc[rr]);
  }
}

// ---------------------------------------------------------------------------
// K2: logits = g @ hr^T + b_bil (f32). 128x128 tile per block, 4 waves (2x2),
// each wave 64x64 via 4x4 fragments of mfma_f32_16x16x32_bf16.
// Epilogue: per-wave online-softmax partials.
//   row partials over this wave's 64 cols  -> rowPM/rowPS[cb64][row], cb64 in [0,96)
//   col partials over this wave's 64 rows  -> colPM/colPS[rb64][col], rb64 in [0,96)
// C-fragment layout: col = bcol + wc*64 + ni*16 + (lane&15),
//                    row = brow + wr*64 + mi*16 + (lane>>4)*4 + qq.
// Row reduce: __shfl_xor 1/2/4/8 (stays within 16-lane group = same row set).
// Col reduce: __shfl_xor 16/32 (crosses groups = same col, different rows).
// ---------------------------------------------------------------------------
__global__ __launch_bounds__(256) void k_gemm(
    const unsigned short* __restrict__ g_bf,   // [NQ][HID]
    const unsigned short* __restrict__ hr_bf,  // [MR][HID]
    const float* __restrict__ b_bil,
    float* __restrict__ logF,
    float* __restrict__ rowPM, float* __restrict__ rowPS,  // [96][NQ]
    float* __restrict__ colPM, float* __restrict__ colPS)  // [96][MR]
{
  const int tid = threadIdx.x;
  const int wid = tid >> 6, lane = tid & 63;
  const int wr = wid >> 1, wc = wid & 1;
  const int brow = blockIdx.x * 128, bcol = blockIdx.y * 128;
  const int l15 = lane & 15;
  const int lk = (lane >> 4) * 8;  // k sub-offset within 32

  const short* A = (const short*)g_bf;
  const short* B = (const short*)hr_bf;

  f32x4 acc[4][4];
#pragma unroll
  for (int i = 0; i < 4; ++i)
#pragma unroll
    for (int j = 0; j < 4; ++j) acc[i][j] = (f32x4)0.0f;

  const short* a_base = A + (size_t)(brow + wr * 64 + l15) * HID + lk;
  const short* b_base = B + (size_t)(bcol + wc * 64 + l15) * HID + lk;

  for (int kk = 0; kk < HID; kk += 32) {
    bf16x8 a[4], b[4];
#pragma unroll
    for (int mi = 0; mi < 4; ++mi)
      a[mi] = *(const bf16x8*)(a_base + (size_t)mi * 16 * HID + kk);
#pragma unroll
    for (int ni = 0; ni < 4; ++ni)
      b[ni] = *(const bf16x8*)(b_base + (size_t)ni * 16 * HID + kk);
#pragma unroll
    for (int mi = 0; mi < 4; ++mi)
#pragma unroll
      for (int ni = 0; ni < 4; ++ni)
        acc[mi][ni] = __builtin_amdgcn_mfma_f32_16x16x32_bf16(
            a[mi], b[ni], acc[mi][ni], 0, 0, 0);
  }

  // fold bias into acc so stores and stats see the same (biased) logits
  const float bb = b_bil[0];
#pragma unroll
  for (int mi = 0; mi < 4; ++mi)
#pragma unroll
    for (int ni = 0; ni < 4; ++ni)
#pragma unroll
      for (int qq = 0; qq < 4; ++qq) acc[mi][ni][qq] += bb;

  // store logits
  const int r0 = brow + wr * 64 + (lane >> 4) * 4;
  const int c0 = bcol + wc * 64 + l15;
#pragma unroll
  for (int mi = 0; mi < 4; ++mi) {
#pragma unroll
    for (int qq = 0; qq < 4; ++qq) {
      const int rr = r0 + mi * 16 + qq;
#pragma unroll
      for (int ni = 0; ni < 4; ++ni) {
        logF[(size_t)rr * MR + c0 + ni * 16] = acc[mi][ni][qq];
      }
    }
  }

  // ---- row partial stats (this wave's 64 cols) ----
  const int cb = blockIdx.y * 2 + wc;
  const int rb = blockIdx.x * 2 + wr;
  const int g = lane >> 4;
#pragma unroll
  for (int mi = 0; mi < 4; ++mi) {
#pragma unroll
    for (int qq = 0; qq < 4; ++qq) {
      float m = fmaxf(fmaxf(acc[mi][0][qq], acc[mi][1][qq]),
                      fmaxf(acc[mi][2][qq], acc[mi][3][qq]));
#pragma unroll
      for (int off = 1; off < 16; off <<= 1)
        m = fmaxf(m, __shfl_xor(m, off));
      float s = 0.0f;
#pragma unroll
      for (int ni = 0; ni < 4; ++ni)
        s += __expf((acc[mi][ni][qq] - m) * INV_T);
#pragma unroll
      for (int off = 1; off < 16; off <<= 1)
        s += __shfl_xor(s, off);
      if (l15 == 0) {
        const int row = brow + wr * 64 + mi * 16 + g * 4 + qq;
        rowPM[(size_t)cb * NQ + row] = m;
        rowPS[(size_t)cb * NQ + row] = s;
      }
    }
  }

  // ---- col partial stats (this wave's 64 rows) ----
#pragma unroll
  for (int ni = 0; ni < 4; ++ni) {
    float m = -INFINITY;
#pragma unroll
    for (int mi = 0; mi < 4; ++mi)
#pragma unroll
      for (int qq = 0; qq < 4; ++qq) m = fmaxf(m, acc[mi][ni][qq]);
    m = fmaxf(m, __shfl_xor(m, 16));
    m = fmaxf(m, __shfl_xor(m, 32));
    float s = 0.0f;
#pragma unroll
    for (int mi = 0; mi < 4; ++mi)
#pragma unroll
      for (int qq = 0; qq < 4; ++qq)
        s += __expf((acc[mi][ni][qq] - m) * INV_T);
    s += __shfl_xor(s, 16);
    s += __shfl_xor(s, 32);
    if (lane < 16) {
      const int col = bcol + wc * 64 + ni * 16 + lane;
      colPM[(size_t)rb * MR + col] = m;
      colPS[(size_t)rb * MR + col] = s;
    }
  }
}

// ---------------------------------------------------------------------------
// K3: combine 96 partials + slack for rows (idx < NQ) and cols (idx >= NQ).
// grid = (NQ+MR)/256 = 48 blocks.
// ---------------------------------------------------------------------------
__global__ __launch_bounds__(256) void k_comb(
    const float* __restrict__ rowPM, const float* __restrict__ rowPS,
    const float* __restrict__ colPM, const float* __restrict__ colPS,
    const float* __restrict__ slack_q, const float* __restrict__ slack_ret,
    float* __restrict__ rowM, float* __restrict__ rowR,
    float* __restrict__ colM, float* __restrict__ colR)
{
  const int idx = blockIdx.x * 256 + threadIdx.x;
  const bool is_row = idx < NQ;
  const int i = is_row ? idx : idx - NQ;
  const float* pm = is_row ? rowPM : colPM;
  const float* ps = is_row ? rowPS : colPS;

  float m = -INFINITY, s = 0.0f;
  for (int c = 0; c < 96; ++c) {
    const float om = pm[(size_t)c * NQ + i];
    const float os = ps[(size_t)c * NQ + i];
    const float nm = fmaxf(m, om);
    s = s * __expf((m - nm) * INV_T) + os * __expf((om - nm) * INV_T);
    m = nm;
  }
  const float sl = is_row ? slack_q[0] : slack_ret[0];
  const float nm = fmaxf(m, sl);
  s = s * __expf((m - nm) * INV_T) + __expf((sl - nm) * INV_T);
  m = nm;

  if (is_row) { rowM[i] = m; rowR[i] = 1.0f / s; }
  else        { colM[i] = m; colR[i] = 1.0f / s; }
}

// ---------------------------------------------------------------------------
// K4: pi = 0.5*(exp((l-rm)/T)*rowR + exp((l-cm)/T)*colR), f32 out.
// ---------------------------------------------------------------------------
__global__ __launch_bounds__(256) void k_final(
    const float* __restrict__ logF,
    const float* __restrict__ rowM, const float* __restrict__ rowR,
    const float* __restrict__ colM, const float* __restrict__ colR,
    float* __restrict__ out_pi)
{
  const int row = blockIdx.x / 6;
  const int seg = blockIdx.x % 6;
  const int col = seg * 1024 + threadIdx.x * 4;
  const size_t base = (size_t)row * MR + col;

  const float rm = rowM[row];
  const float rr = rowR[row];
  const f32x4 cm = *(const f32x4*)(&colM[col]);
  const f32x4 cr = *(const f32x4*)(&colR[col]);
  const f32x4 l4 = *(const f32x4*)(logF + base);

  f32x4 o;
  o.x = 0.5f * (__expf((l4.x - rm) * INV_T) * rr + __expf((l4.x - cm.x) * INV_T) * cr.x);
  o.y = 0.5f * (__expf((l4.y - rm) * INV_T) * rr + __expf((l4.y - cm.y) * INV_T) * cr.y);
  o.z = 0.5f * (__expf((l4.z - rm) * INV_T) * rr + __expf((l4.z - cm.z) * INV_T) * cr.z);
  o.w = 0.5f * (__expf((l4.w - rm) * INV_T) * rr + __expf((l4.w - cm.w) * INV_T) * cr.w);
  *(f32x4*)(out_pi + base) = o;
}

// ---------------------------------------------------------------------------
extern "C" void kernel_launch(void* const* d_in, const int* in_sizes, int n_in,
                              void* d_out, int out_size, void* d_ws, size_t ws_size,
                              hipStream_t stream) {
  const float* q  = (const float*)d_in[0];
  const float* r  = (const float*)d_in[1];
  const float* W1 = (const float*)d_in[2];
  const float* b1 = (const float*)d_in[3];
  const float* W2 = (const float*)d_in[4];
  const float* b2 = (const float*)d_in[5];
  const float* Wb = (const float*)d_in[6];
  const float* bb = (const float*)d_in[7];
  const float* sq = (const float*)d_in[8];
  const float* sr = (const float*)d_in[9];

  float* out_pi = (float*)d_out;                      // [NQ][MR] f32
  float* out_lg = out_pi + (size_t)NQ * MR;           // [NQ][MR] f32 logits

  char* w = (char*)d_ws;
  size_t off = 0;
  auto alloc = [&](size_t bytes) {
    void* p = w + off;
    off += (bytes + 255) & ~(size_t)255;
    return p;
  };
  unsigned short* g_bf  = (unsigned short*)alloc((size_t)NQ * HID * 2);
  unsigned short* hr_bf = (unsigned short*)alloc((size_t)MR * HID * 2);
  float* rowM = (float*)alloc((size_t)NQ * 4);
  float* rowR = (float*)alloc((size_t)NQ * 4);
  float* colM = (float*)alloc((size_t)MR * 4);
  float* colR = (float*)alloc((size_t)MR * 4);

  // Partial-stat slabs live in out_pi, which is dead until k_final rewrites it.
  // 4 slabs x 96 x 6144 floats = 9.4 MB << 151 MB.
  float* rowPM = out_pi + (size_t)0 * 96 * NQ;
  float* rowPS = out_pi + (size_t)1 * 96 * NQ;
  float* colPM = out_pi + (size_t)2 * 96 * NQ;
  float* colPS = out_pi + (size_t)3 * 96 * NQ;

  k_compress<<<dim3((NQ + MR) / 16), 256, 0, stream>>>(q, r, W1, b1, W2, b2, Wb,
                                                       g_bf, hr_bf);
  k_gemm<<<dim3(NQ / 128, MR / 128), 256, 0, stream>>>(
      g_bf, hr_bf, bb, out_lg, rowPM, rowPS, colPM, colPS);
  k_comb<<<dim3((NQ + MR) / 256), 256, 0, stream>>>(
      rowPM, rowPS, colPM, colPS, sq, sr, rowM, rowR, colM, colR);
  k_final<<<dim3(NQ * 6), 256, 0, stream>>>(out_lg, rowM, rowR, colM, colR, out_pi);
}

// Round 2
// 175.253 us; speedup vs baseline: 1.4986x; 1.3608x over previous
//
#include <hip/hip_runtime.h>
#include <hip/hip_bf16.h>
#include <math.h>

#define NQ 6144
#define MR 6144
#define DIN 16
#define HID 256
#define INV_T 10.0f

typedef __attribute__((ext_vector_type(4))) float f32x4;
typedef __attribute__((ext_vector_type(8))) short bf16x8;

static __device__ __forceinline__ unsigned short f2bf(float f) {
  __hip_bfloat16 h = __float2bfloat16(f);
  return __builtin_bit_cast(unsigned short, h);
}

// ---------------------------------------------------------------------------
// K0: prep — W2 -> bf16 (row-major [c][k], already B-operand layout),
//           Wb -> bf16 transposed ([c][j], B-operand layout for phase 3).
// 65536 elems, 256 blocks x 256 thr.
// ---------------------------------------------------------------------------
__global__ __launch_bounds__(256) void k_prep(
    const float* __restrict__ W2, const float* __restrict__ Wb,
    unsigned short* __restrict__ W2bf, unsigned short* __restrict__ Wbt)
{
  const int idx = blockIdx.x * 256 + threadIdx.x;  // = j*256 + c
  W2bf[idx] = f2bf(W2[idx]);
  const int j = idx >> 8, c = idx & 255;
  Wbt[(size_t)c * 256 + j] = f2bf(Wb[idx]);
}

// ---------------------------------------------------------------------------
// K1: compress, MFMA version. 16 rows/block, 256 thr (4 waves).
// phase1 (VALU, exact): t = gelu(x@W1^T + b1)   -> bf16 in LDS (swizzled)
// phase2 (MFMA):        h = t@W2^T + b2         -> bf16 in LDS (swizzled)
//   ret rows: coalesced store h -> hr_bf.
// phase3 (MFMA, q only): g = h@Wb               -> staged, coalesced -> g_bf
// LDS swizzle: elem index = row*256 + (k ^ ((row&7)<<3)) — breaks the
// 16-way bank conflict of stride-512B rows on ds_read_b128 (G4/T2).
// ---------------------------------------------------------------------------
__global__ __launch_bounds__(256) void k_compress(
    const float* __restrict__ q, const float* __restrict__ ret,
    const float* __restrict__ W1, const float* __restrict__ b1,
    const unsigned short* __restrict__ W2bf, const float* __restrict__ b2,
    const unsigned short* __restrict__ Wbt,
    unsigned short* __restrict__ g_bf, unsigned short* __restrict__ hr_bf)
{
  const int tid = threadIdx.x;
  const bool is_q = blockIdx.x < (NQ / 16);
  const int row0 = (is_q ? blockIdx.x : blockIdx.x - NQ / 16) * 16;
  const float* x = is_q ? q : ret;

  __shared__ float xs[16][DIN];
  __shared__ __align__(16) unsigned short tb[16 * 256];
  __shared__ __align__(16) unsigned short hb[16 * 256];

  // load x rows: 16*16 = 256 floats
  ((float*)xs)[tid] = x[(size_t)row0 * DIN + tid];
  __syncthreads();

  // ---- phase 1: t[rr][tid] = gelu(...), store bf16 swizzled ----
  {
    float w[DIN];
#pragma unroll
    for (int d = 0; d < DIN; ++d) w[d] = W1[tid * DIN + d];
    const float bb = b1[tid];
#pragma unroll
    for (int rr = 0; rr < 16; ++rr) {
      float a = bb;
#pragma unroll
      for (int d = 0; d < DIN; ++d) a += xs[rr][d] * w[d];
      a = 0.5f * a * (1.0f + erff(a * 0.70710678118654752f));
      tb[rr * 256 + (tid ^ ((rr & 7) << 3))] = f2bf(a);
    }
  }
  __syncthreads();

  const int wid = tid >> 6, lane = tid & 63;
  const int l15 = lane & 15;
  const int lk = (lane >> 4) * 8;

  // ---- phase 2: h = t @ W2^T + b2 via MFMA. wave wid owns cols wid*64..+63 ----
  {
    f32x4 acc[4];
#pragma unroll
    for (int ci = 0; ci < 4; ++ci) acc[ci] = (f32x4)0.0f;

    for (int kk = 0; kk < HID; kk += 32) {
      const bf16x8 a = *(const bf16x8*)&tb[l15 * 256 + ((kk + lk) ^ ((l15 & 7) << 3))];
#pragma unroll
      for (int ci = 0; ci < 4; ++ci) {
        const int bc = wid * 64 + ci * 16 + l15;
        const bf16x8 b = *(const bf16x8*)&W2bf[(size_t)bc * HID + kk + lk];
        acc[ci] = __builtin_amdgcn_mfma_f32_16x16x32_bf16(a, b, acc[ci], 0, 0, 0);
      }
    }

    // h = acc + b2 -> hb (bf16, swizzled). C layout: col=l15, row=(lane>>4)*4+q
#pragma unroll
    for (int ci = 0; ci < 4; ++ci) {
      const int col = wid * 64 + ci * 16 + l15;
      const float bb2 = b2[col];
#pragma unroll
      for (int qq = 0; qq < 4; ++qq) {
        const int row = (lane >> 4) * 4 + qq;
        hb[row * 256 + (col ^ ((row & 7) << 3))] = f2bf(acc[ci][qq] + bb2);
      }
    }
  }
  __syncthreads();

  if (!is_q) {
    // coalesced store: thread -> (row = tid>>4, k0 = (tid&15)*16)
    const int row = tid >> 4;
    const int k0 = (tid & 15) * 16;
#pragma unroll
    for (int i = 0; i < 2; ++i) {
      const bf16x8 v = *(const bf16x8*)&hb[row * 256 + ((k0 + 8 * i) ^ ((row & 7) << 3))];
      *(bf16x8*)&hr_bf[(size_t)(row0 + row) * HID + k0 + 8 * i] = v;
    }
    return;
  }

  // ---- phase 3 (q only): g = h @ Wb via MFMA (B = Wb^T, prepped) ----
  {
    f32x4 acc[4];
#pragma unroll
    for (int ci = 0; ci < 4; ++ci) acc[ci] = (f32x4)0.0f;

    for (int kk = 0; kk < HID; kk += 32) {
      const bf16x8 a = *(const bf16x8*)&hb[l15 * 256 + ((kk + lk) ^ ((l15 & 7) << 3))];
#pragma unroll
      for (int ci = 0; ci < 4; ++ci) {
        const int bc = wid * 64 + ci * 16 + l15;
        const bf16x8 b = *(const bf16x8*)&Wbt[(size_t)bc * HID + kk + lk];
        acc[ci] = __builtin_amdgcn_mfma_f32_16x16x32_bf16(a, b, acc[ci], 0, 0, 0);
      }
    }

    // stage g into tb (dead now), swizzled
#pragma unroll
    for (int ci = 0; ci < 4; ++ci) {
      const int col = wid * 64 + ci * 16 + l15;
#pragma unroll
      for (int qq = 0; qq < 4; ++qq) {
        const int row = (lane >> 4) * 4 + qq;
        tb[row * 256 + (col ^ ((row & 7) << 3))] = f2bf(acc[ci][qq]);
      }
    }
  }
  __syncthreads();

  {
    const int row = tid >> 4;
    const int k0 = (tid & 15) * 16;
#pragma unroll
    for (int i = 0; i < 2; ++i) {
      const bf16x8 v = *(const bf16x8*)&tb[row * 256 + ((k0 + 8 * i) ^ ((row & 7) << 3))];
      *(bf16x8*)&g_bf[(size_t)(row0 + row) * HID + k0 + 8 * i] = v;
    }
  }
}

// ---------------------------------------------------------------------------
// K2: logits = g @ hr^T + b_bil (f32). 128x128 tile per block, 4 waves (2x2),
// each wave 64x64 via 4x4 fragments of mfma_f32_16x16x32_bf16.
// Epilogue: per-wave online-softmax partials (row over 64 cols, col over 64 rows).
// ---------------------------------------------------------------------------
__global__ __launch_bounds__(256) void k_gemm(
    const unsigned short* __restrict__ g_bf,   // [NQ][HID]
    const unsigned short* __restrict__ hr_bf,  // [MR][HID]
    const float* __restrict__ b_bil,
    float* __restrict__ logF,
    float* __restrict__ rowPM, float* __restrict__ rowPS,  // [96][NQ]
    float* __restrict__ colPM, float* __restrict__ colPS)  // [96][MR]
{
  const int tid = threadIdx.x;
  const int wid = tid >> 6, lane = tid & 63;
  const int wr = wid >> 1, wc = wid & 1;
  const int brow = blockIdx.x * 128, bcol = blockIdx.y * 128;
  const int l15 = lane & 15;
  const int lk = (lane >> 4) * 8;

  const short* A = (const short*)g_bf;
  const short* B = (const short*)hr_bf;

  f32x4 acc[4][4];
#pragma unroll
  for (int i = 0; i < 4; ++i)
#pragma unroll
    for (int j = 0; j < 4; ++j) acc[i][j] = (f32x4)0.0f;

  const short* a_base = A + (size_t)(brow + wr * 64 + l15) * HID + lk;
  const short* b_base = B + (size_t)(bcol + wc * 64 + l15) * HID + lk;

  for (int kk = 0; kk < HID; kk += 32) {
    bf16x8 a[4], b[4];
#pragma unroll
    for (int mi = 0; mi < 4; ++mi)
      a[mi] = *(const bf16x8*)(a_base + (size_t)mi * 16 * HID + kk);
#pragma unroll
    for (int ni = 0; ni < 4; ++ni)
      b[ni] = *(const bf16x8*)(b_base + (size_t)ni * 16 * HID + kk);
#pragma unroll
    for (int mi = 0; mi < 4; ++mi)
#pragma unroll
      for (int ni = 0; ni < 4; ++ni)
        acc[mi][ni] = __builtin_amdgcn_mfma_f32_16x16x32_bf16(
            a[mi], b[ni], acc[mi][ni], 0, 0, 0);
  }

  const float bb = b_bil[0];
#pragma unroll
  for (int mi = 0; mi < 4; ++mi)
#pragma unroll
    for (int ni = 0; ni < 4; ++ni)
#pragma unroll
      for (int qq = 0; qq < 4; ++qq) acc[mi][ni][qq] += bb;

  const int r0 = brow + wr * 64 + (lane >> 4) * 4;
  const int c0 = bcol + wc * 64 + l15;
#pragma unroll
  for (int mi = 0; mi < 4; ++mi) {
#pragma unroll
    for (int qq = 0; qq < 4; ++qq) {
      const int rr = r0 + mi * 16 + qq;
#pragma unroll
      for (int ni = 0; ni < 4; ++ni) {
        logF[(size_t)rr * MR + c0 + ni * 16] = acc[mi][ni][qq];
      }
    }
  }

  // ---- row partial stats (this wave's 64 cols) ----
  const int cb = blockIdx.y * 2 + wc;
  const int rb = blockIdx.x * 2 + wr;
  const int g = lane >> 4;
#pragma unroll
  for (int mi = 0; mi < 4; ++mi) {
#pragma unroll
    for (int qq = 0; qq < 4; ++qq) {
      float m = fmaxf(fmaxf(acc[mi][0][qq], acc[mi][1][qq]),
                      fmaxf(acc[mi][2][qq], acc[mi][3][qq]));
#pragma unroll
      for (int off = 1; off < 16; off <<= 1)
        m = fmaxf(m, __shfl_xor(m, off));
      float s = 0.0f;
#pragma unroll
      for (int ni = 0; ni < 4; ++ni)
        s += __expf((acc[mi][ni][qq] - m) * INV_T);
#pragma unroll
      for (int off = 1; off < 16; off <<= 1)
        s += __shfl_xor(s, off);
      if (l15 == 0) {
        const int row = brow + wr * 64 + mi * 16 + g * 4 + qq;
        rowPM[(size_t)cb * NQ + row] = m;
        rowPS[(size_t)cb * NQ + row] = s;
      }
    }
  }

  // ---- col partial stats (this wave's 64 rows) ----
#pragma unroll
  for (int ni = 0; ni < 4; ++ni) {
    float m = -INFINITY;
#pragma unroll
    for (int mi = 0; mi < 4; ++mi)
#pragma unroll
      for (int qq = 0; qq < 4; ++qq) m = fmaxf(m, acc[mi][ni][qq]);
    m = fmaxf(m, __shfl_xor(m, 16));
    m = fmaxf(m, __shfl_xor(m, 32));
    float s = 0.0f;
#pragma unroll
    for (int mi = 0; mi < 4; ++mi)
#pragma unroll
      for (int qq = 0; qq < 4; ++qq)
        s += __expf((acc[mi][ni][qq] - m) * INV_T);
    s += __shfl_xor(s, 16);
    s += __shfl_xor(s, 32);
    if (lane < 16) {
      const int col = bcol + wc * 64 + ni * 16 + lane;
      colPM[(size_t)rb * MR + col] = m;
      colPS[(size_t)rb * MR + col] = s;
    }
  }
}

// ---------------------------------------------------------------------------
// K3: combine 96 partials + slack for rows (idx < NQ) and cols (idx >= NQ).
// ---------------------------------------------------------------------------
__global__ __launch_bounds__(256) void k_comb(
    const float* __restrict__ rowPM, const float* __restrict__ rowPS,
    const float* __restrict__ colPM, const float* __restrict__ colPS,
    const float* __restrict__ slack_q, const float* __restrict__ slack_ret,
    float* __restrict__ rowM, float* __restrict__ rowR,
    float* __restrict__ colM, float* __restrict__ colR)
{
  const int idx = blockIdx.x * 256 + threadIdx.x;
  const bool is_row = idx < NQ;
  const int i = is_row ? idx : idx - NQ;
  const float* pm = is_row ? rowPM : colPM;
  const float* ps = is_row ? rowPS : colPS;

  float m = -INFINITY, s = 0.0f;
  for (int c = 0; c < 96; ++c) {
    const float om = pm[(size_t)c * NQ + i];
    const float os = ps[(size_t)c * NQ + i];
    const float nm = fmaxf(m, om);
    s = s * __expf((m - nm) * INV_T) + os * __expf((om - nm) * INV_T);
    m = nm;
  }
  const float sl = is_row ? slack_q[0] : slack_ret[0];
  const float nm = fmaxf(m, sl);
  s = s * __expf((m - nm) * INV_T) + __expf((sl - nm) * INV_T);
  m = nm;

  if (is_row) { rowM[i] = m; rowR[i] = 1.0f / s; }
  else        { colM[i] = m; colR[i] = 1.0f / s; }
}

// ---------------------------------------------------------------------------
// K4: pi = 0.5*(exp((l-rm)/T)*rowR + exp((l-cm)/T)*colR), f32 out.
// ---------------------------------------------------------------------------
__global__ __launch_bounds__(256) void k_final(
    const float* __restrict__ logF,
    const float* __restrict__ rowM, const float* __restrict__ rowR,
    const float* __restrict__ colM, const float* __restrict__ colR,
    float* __restrict__ out_pi)
{
  const int row = blockIdx.x / 6;
  const int seg = blockIdx.x % 6;
  const int col = seg * 1024 + threadIdx.x * 4;
  const size_t base = (size_t)row * MR + col;

  const float rm = rowM[row];
  const float rr = rowR[row];
  const f32x4 cm = *(const f32x4*)(&colM[col]);
  const f32x4 cr = *(const f32x4*)(&colR[col]);
  const f32x4 l4 = *(const f32x4*)(logF + base);

  f32x4 o;
  o.x = 0.5f * (__expf((l4.x - rm) * INV_T) * rr + __expf((l4.x - cm.x) * INV_T) * cr.x);
  o.y = 0.5f * (__expf((l4.y - rm) * INV_T) * rr + __expf((l4.y - cm.y) * INV_T) * cr.y);
  o.z = 0.5f * (__expf((l4.z - rm) * INV_T) * rr + __expf((l4.z - cm.z) * INV_T) * cr.z);
  o.w = 0.5f * (__expf((l4.w - rm) * INV_T) * rr + __expf((l4.w - cm.w) * INV_T) * cr.w);
  *(f32x4*)(out_pi + base) = o;
}

// ---------------------------------------------------------------------------
extern "C" void kernel_launch(void* const* d_in, const int* in_sizes, int n_in,
                              void* d_out, int out_size, void* d_ws, size_t ws_size,
                              hipStream_t stream) {
  const float* q  = (const float*)d_in[0];
  const float* r  = (const float*)d_in[1];
  const float* W1 = (const float*)d_in[2];
  const float* b1 = (const float*)d_in[3];
  const float* W2 = (const float*)d_in[4];
  const float* b2 = (const float*)d_in[5];
  const float* Wb = (const float*)d_in[6];
  const float* bb = (const float*)d_in[7];
  const float* sq = (const float*)d_in[8];
  const float* sr = (const float*)d_in[9];

  float* out_pi = (float*)d_out;                      // [NQ][MR] f32
  float* out_lg = out_pi + (size_t)NQ * MR;           // [NQ][MR] f32 logits

  char* w = (char*)d_ws;
  size_t off = 0;
  auto alloc = [&](size_t bytes) {
    void* p = w + off;
    off += (bytes + 255) & ~(size_t)255;
    return p;
  };
  unsigned short* g_bf  = (unsigned short*)alloc((size_t)NQ * HID * 2);
  unsigned short* hr_bf = (unsigned short*)alloc((size_t)MR * HID * 2);
  unsigned short* W2bf  = (unsigned short*)alloc((size_t)HID * HID * 2);
  unsigned short* Wbt   = (unsigned short*)alloc((size_t)HID * HID * 2);
  float* rowM = (float*)alloc((size_t)NQ * 4);
  float* rowR = (float*)alloc((size_t)NQ * 4);
  float* colM = (float*)alloc((size_t)MR * 4);
  float* colR = (float*)alloc((size_t)MR * 4);

  // Partial-stat slabs live in out_pi (dead until k_final rewrites it).
  float* rowPM = out_pi + (size_t)0 * 96 * NQ;
  float* rowPS = out_pi + (size_t)1 * 96 * NQ;
  float* colPM = out_pi + (size_t)2 * 96 * NQ;
  float* colPS = out_pi + (size_t)3 * 96 * NQ;

  k_prep<<<dim3(HID * HID / 256), 256, 0, stream>>>(W2, Wb, W2bf, Wbt);
  k_compress<<<dim3((NQ + MR) / 16), 256, 0, stream>>>(q, r, W1, b1, W2bf, b2,
                                                       Wbt, g_bf, hr_bf);
  k_gemm<<<dim3(NQ / 128, MR / 128), 256, 0, stream>>>(
      g_bf, hr_bf, bb, out_lg, rowPM, rowPS, colPM, colPS);
  k_comb<<<dim3((NQ + MR) / 256), 256, 0, stream>>>(
      rowPM, rowPS, colPM, colPS, sq, sr, rowM, rowR, colM, colR);
  k_final<<<dim3(NQ * 6), 256, 0, stream>>>(out_lg, rowM, rowR, colM, colR, out_pi);
}